// Round 7
// baseline (178.536 us; speedup 1.0000x reference)
//
#include <hip/hip_runtime.h>
#include <hip/hip_bf16.h>

#define B_ 8
#define T_ 2048
#define C_ 768
#define H_ 64
#define BT_ (B_*T_)

typedef __attribute__((ext_vector_type(8))) short bf16x8;
typedef __attribute__((ext_vector_type(4))) float f32x4;

__device__ __forceinline__ unsigned short f2bf(float x) {
    __hip_bfloat16 h = __float2bfloat16(x);   // RNE
    return __builtin_bit_cast(unsigned short, h);
}

__device__ __forceinline__ bf16x8 cvt8(float4 a, float4 b) {
    bf16x8 r;
    r[0] = (short)f2bf(a.x); r[1] = (short)f2bf(a.y);
    r[2] = (short)f2bf(a.z); r[3] = (short)f2bf(a.w);
    r[4] = (short)f2bf(b.x); r[5] = (short)f2bf(b.y);
    r[6] = (short)f2bf(b.z); r[7] = (short)f2bf(b.w);
    return r;
}

// ------------- W prep (coalesced LDS transpose): WT[m*64+n][k] = bf16(W_m[k][n])
__global__ __launch_bounds__(256) void wprep(
    const float* __restrict__ Wq, const float* __restrict__ Wk,
    const float* __restrict__ Wv, unsigned short* __restrict__ WT)
{
    __shared__ float tile[64][65];
    const int bidx = blockIdx.x;             // 36 = 3 m * 12 k-tiles
    const int m = bidx / 12, kt = bidx % 12;
    const float* __restrict__ W = (m == 0) ? Wq : (m == 1) ? Wk : Wv;
    const int t = threadIdx.x;
    const int n = t & 63, kr = t >> 6;
    #pragma unroll
    for (int r = kr; r < 64; r += 4)
        tile[r][n] = W[(size_t)(kt * 64 + r) * H_ + n];   // coalesced 256B rows
    __syncthreads();
    const int n2 = t >> 2, k0 = (t & 3) * 16;
    #pragma unroll
    for (int g = 0; g < 4; g++) {
        ushort4 u;
        u.x = f2bf(tile[k0 + g * 4 + 0][n2]);
        u.y = f2bf(tile[k0 + g * 4 + 1][n2]);
        u.z = f2bf(tile[k0 + g * 4 + 2][n2]);
        u.w = f2bf(tile[k0 + g * 4 + 3][n2]);
        *(ushort4*)(WT + (size_t)(m * 64 + n2) * C_ + kt * 64 + k0 + g * 4) = u;
    }
}

// ------------- QKV via MFMA: 1 wave/block, no LDS, deep register prefetch -------
// Wave = 16 tokens x 3 f-groups over full C=768 (complete dot products; no merge).
// W prefetched 4 chunks deep (12 loads in flight), x 2 deep (4 loads).
// __launch_bounds__(64,4) gives the allocator ~128 VGPRs: R4-R6 showed the
// compiler starving MLP at 36-60 VGPRs when targeting occupancy the 4-block/CU
// grid could not use anyway.
__global__ __launch_bounds__(64, 4) void qkv_kernel(
    const float* __restrict__ x, const unsigned short* __restrict__ WT,
    unsigned short* __restrict__ qo, unsigned short* __restrict__ ko,
    unsigned short* __restrict__ vTo)
{
    const int lane = threadIdx.x;
    const int q16  = lane & 15, quad = lane >> 4;
    const int bid  = blockIdx.x;
    const int tile = bid >> 2;
    const int w    = bid & 3;                // f-set 0..3
    const int f0   = w * 3;
    const int rowBase = tile << 4;
    const int row  = rowBase + q16;
    const int b    = rowBase >> 11, t0 = rowBase & (T_ - 1);

    // chunk c covers k = c*32..c*32+31; lane's slice: quad*8..quad*8+7
    const float* __restrict__ xp = x + (size_t)row * C_ + quad * 8;
    const unsigned short* __restrict__ wp = WT + (size_t)(f0 * 16 + q16) * C_ + quad * 8;

    bf16x8 wbuf[4][3];                       // 4-deep W prefetch ring
    float4 xbuf[2][2];                       // 2-deep x prefetch ring
    #pragma unroll
    for (int d = 0; d < 4; d++)
        #pragma unroll
        for (int j = 0; j < 3; j++)
            wbuf[d][j] = *(const bf16x8*)(wp + d * 32 + (size_t)j * 16 * C_);
    #pragma unroll
    for (int d = 0; d < 2; d++) {
        xbuf[d][0] = *(const float4*)(xp + d * 32);
        xbuf[d][1] = *(const float4*)(xp + d * 32 + 4);
    }

    f32x4 acc[3] = {};
    #pragma unroll
    for (int c = 0; c < 24; c++) {
        bf16x8 w0 = wbuf[c & 3][0], w1 = wbuf[c & 3][1], w2 = wbuf[c & 3][2];
        bf16x8 xf = cvt8(xbuf[c & 1][0], xbuf[c & 1][1]);
        if (c + 2 < 24) {                    // static (loop fully unrolled)
            xbuf[c & 1][0] = *(const float4*)(xp + (c + 2) * 32);
            xbuf[c & 1][1] = *(const float4*)(xp + (c + 2) * 32 + 4);
        }
        if (c + 4 < 24) {
            #pragma unroll
            for (int j = 0; j < 3; j++)
                wbuf[c & 3][j] = *(const bf16x8*)(wp + (c + 4) * 32 + (size_t)j * 16 * C_);
        }
        acc[0] = __builtin_amdgcn_mfma_f32_16x16x32_bf16(w0, xf, acc[0], 0, 0, 0);
        acc[1] = __builtin_amdgcn_mfma_f32_16x16x32_bf16(w1, xf, acc[1], 0, 0, 0);
        acc[2] = __builtin_amdgcn_mfma_f32_16x16x32_bf16(w2, xf, acc[2], 0, 0, 0);
    }

    #pragma unroll
    for (int j = 0; j < 3; j++) {
        const int f = f0 + j;                // wave-uniform
        if (f < 8) {
            ushort4 u;
            u.x = f2bf(acc[j][0]); u.y = f2bf(acc[j][1]);
            u.z = f2bf(acc[j][2]); u.w = f2bf(acc[j][3]);
            unsigned short* __restrict__ dst = (f < 4) ? qo : ko;
            *(ushort4*)(dst + (size_t)row * H_ + (f & 3) * 16 + quad * 4) = u;
        } else {
            #pragma unroll
            for (int r = 0; r < 4; r++) {
                int h = (f - 8) * 16 + quad * 4 + r;
                vTo[((size_t)(b * H_) + h) * T_ + t0 + q16] = f2bf(acc[j][r]);
            }
        }
    }
}

// ------------- MFMA flash attention: 4 waves/block k-split, NO in-loop barriers -
__global__ __launch_bounds__(256) void attn_kernel(
    const unsigned short* __restrict__ qB, const unsigned short* __restrict__ kB,
    const unsigned short* __restrict__ vT, const float* __restrict__ mask,
    float* __restrict__ out)
{
    __shared__ __align__(16) unsigned short pS[4][16][88];  // wave-private P tiles
    __shared__ float oS[3][64][17];
    __shared__ float mlS[3][64][2];

    const int tid  = threadIdx.x;
    const int w    = tid >> 6;
    const int lane = tid & 63;
    const int q16  = lane & 15;
    const int quad = lane >> 4;
    const int bid  = blockIdx.x;
    const int b    = bid & 7;                    // batches interleaved
    const int qt   = 127 - (bid >> 3);           // heavy q-tiles first
    const int qrow = (qt << 4) + q16;

    const size_t qoff = ((size_t)(b * T_) + qrow) * H_ + quad * 8;
    bf16x8 qf0 = *(const bf16x8*)(qB + qoff);
    bf16x8 qf1 = *(const bf16x8*)(qB + qoff + 32);
    // fold 1/sqrt(64) and log2(e): softmax runs in base-2 domain
    const float maskv = mask[b * T_ + qrow] * 0.125f * 1.44269504f;

    f32x4 o[4] = {};
    float m_run = -__builtin_inff();
    float l_run = 0.f;

    const int niter = ((qt << 4) + 16 + 63) >> 6;   // 64-wide k tiles
    for (int kt = w; kt < niter; kt += 4) {
        const int kbase = kt << 6;

        // ---- K and V fragment loads (issued together; V covers softmax latency)
        bf16x8 kf[8], vf[8];
        #pragma unroll
        for (int sub = 0; sub < 4; sub++) {
            const unsigned short* kp = kB + ((size_t)(b * T_) + kbase + sub * 16 + q16) * H_ + quad * 8;
            kf[2 * sub]     = *(const bf16x8*)(kp);
            kf[2 * sub + 1] = *(const bf16x8*)(kp + 32);
        }
        #pragma unroll
        for (int ht = 0; ht < 4; ht++) {
            const unsigned short* vp = vT + ((size_t)(b * H_) + ht * 16 + q16) * T_ + kbase + quad * 8;
            vf[2 * ht]     = *(const bf16x8*)(vp);
            vf[2 * ht + 1] = *(const bf16x8*)(vp + 32);
        }

        // ---- S^T = K.Q^T : D[k_local][q]
        f32x4 sa[4] = {};
        #pragma unroll
        for (int sub = 0; sub < 4; sub++) {
            sa[sub] = __builtin_amdgcn_mfma_f32_16x16x32_bf16(kf[2 * sub],     qf0, sa[sub], 0, 0, 0);
            sa[sub] = __builtin_amdgcn_mfma_f32_16x16x32_bf16(kf[2 * sub + 1], qf1, sa[sub], 0, 0, 0);
        }

        // ---- reference semantics: s = mask*qk/8 (log2 dom); s==0 -> -inf; causal
        float s[16];
        #pragma unroll
        for (int sub = 0; sub < 4; sub++)
            #pragma unroll
            for (int r = 0; r < 4; r++) {
                int kidx = kbase + sub * 16 + quad * 4 + r;
                float sv = sa[sub][r] * maskv;
                sv = (sv == 0.f) ? -__builtin_inff() : sv;
                sv = (kidx > qrow) ? -__builtin_inff() : sv;
                s[sub * 4 + r] = sv;
            }

        // ---- online softmax (base-2). xor-16/32 reduce across the 4 lane-quads.
        float mx = s[0];
        #pragma unroll
        for (int i2 = 1; i2 < 16; i2++) mx = fmaxf(mx, s[i2]);
        mx = fmaxf(mx, __shfl_xor(mx, 16));
        mx = fmaxf(mx, __shfl_xor(mx, 32));
        float m_new = fmaxf(m_run, mx);
        float m_use = (m_new == -__builtin_inff()) ? 0.f : m_new;
        float alpha = exp2f(m_run - m_use);
        float p[16], psum = 0.f;
        #pragma unroll
        for (int i2 = 0; i2 < 16; i2++) { p[i2] = exp2f(s[i2] - m_use); psum += p[i2]; }
        psum += __shfl_xor(psum, 16);
        psum += __shfl_xor(psum, 32);
        l_run = l_run * alpha + psum;
        m_run = m_new;
        #pragma unroll
        for (int ht = 0; ht < 4; ht++)
            #pragma unroll
            for (int r = 0; r < 4; r++) o[ht][r] *= alpha;

        // ---- P^T -> wave-private LDS as P[q][k] bf16 (intra-wave: no barrier)
        #pragma unroll
        for (int sub = 0; sub < 4; sub++) {
            unsigned int lo = (unsigned int)f2bf(p[sub * 4 + 0]) | ((unsigned int)f2bf(p[sub * 4 + 1]) << 16);
            unsigned int hi = (unsigned int)f2bf(p[sub * 4 + 2]) | ((unsigned int)f2bf(p[sub * 4 + 3]) << 16);
            *(uint2*)&pS[w][q16][sub * 16 + quad * 4] = make_uint2(lo, hi);
        }
        bf16x8 pf0 = *(const bf16x8*)&pS[w][q16][quad * 8];
        bf16x8 pf1 = *(const bf16x8*)&pS[w][q16][32 + quad * 8];

        // ---- O^T += V^T.P^T
        #pragma unroll
        for (int ht = 0; ht < 4; ht++) {
            o[ht] = __builtin_amdgcn_mfma_f32_16x16x32_bf16(vf[2 * ht],     pf0, o[ht], 0, 0, 0);
            o[ht] = __builtin_amdgcn_mfma_f32_16x16x32_bf16(vf[2 * ht + 1], pf1, o[ht], 0, 0, 0);
        }
    }

    // ---- merge the 4 waves' online-softmax states
    if (w > 0) {
        mlS[w - 1][lane][0] = m_run;
        mlS[w - 1][lane][1] = l_run;
        #pragma unroll
        for (int ht = 0; ht < 4; ht++)
            #pragma unroll
            for (int r = 0; r < 4; r++) oS[w - 1][lane][ht * 4 + r] = o[ht][r];
    }
    __syncthreads();
    if (w == 0) {
        float mm[3], ll[3];
        float m = m_run;
        #pragma unroll
        for (int j = 0; j < 3; j++) {
            mm[j] = mlS[j][lane][0]; ll[j] = mlS[j][lane][1];
            m = fmaxf(m, mm[j]);
        }
        float mu = (m == -__builtin_inff()) ? 0.f : m;
        float a0 = exp2f(m_run - mu);
        float aj[3];
        float l = l_run * a0;
        #pragma unroll
        for (int j = 0; j < 3; j++) { aj[j] = exp2f(mm[j] - mu); l += ll[j] * aj[j]; }
        float invl = (l > 0.f) ? (1.f / l) : 0.f;   // fully-masked row -> 0
        #pragma unroll
        for (int ht = 0; ht < 4; ht++) {
            float4 ov;
            float vx = o[ht][0] * a0, vy = o[ht][1] * a0, vz = o[ht][2] * a0, vw2 = o[ht][3] * a0;
            #pragma unroll
            for (int j = 0; j < 3; j++) {
                vx += oS[j][lane][ht * 4 + 0] * aj[j];
                vy += oS[j][lane][ht * 4 + 1] * aj[j];
                vz += oS[j][lane][ht * 4 + 2] * aj[j];
                vw2 += oS[j][lane][ht * 4 + 3] * aj[j];
            }
            ov.x = vx * invl; ov.y = vy * invl; ov.z = vz * invl; ov.w = vw2 * invl;
            *(float4*)(out + ((size_t)(b * T_) + qrow) * H_ + ht * 16 + quad * 4) = ov;
        }
    }
}

extern "C" void kernel_launch(void* const* d_in, const int* in_sizes, int n_in,
                              void* d_out, int out_size, void* d_ws, size_t ws_size,
                              hipStream_t stream) {
    const float* x    = (const float*)d_in[0];
    const float* mask = (const float*)d_in[1];
    const float* Wq   = (const float*)d_in[2];
    const float* Wk   = (const float*)d_in[3];
    const float* Wv   = (const float*)d_in[4];
    float* out = (float*)d_out;

    unsigned short* qw = (unsigned short*)d_ws;            // bf16 [B,T,H]
    unsigned short* kw = qw + (size_t)BT_ * H_;            // bf16 [B,T,H]
    unsigned short* vw = kw + (size_t)BT_ * H_;            // bf16 [B,H,T]
    unsigned short* wt = vw + (size_t)BT_ * H_;            // bf16 [192][768]

    wprep<<<36, 256, 0, stream>>>(Wq, Wk, Wv, wt);
    qkv_kernel<<<BT_ / 16 * 4, 64, 0, stream>>>(x, wt, qw, kw, vw);
    attn_kernel<<<B_ * (T_ / 16), 256, 0, stream>>>(qw, kw, vw, mask, out);
}

// Round 8
// 165.125 us; speedup vs baseline: 1.0812x; 1.0812x over previous
//
#include <hip/hip_runtime.h>
#include <hip/hip_bf16.h>

#define B_ 8
#define T_ 2048
#define C_ 768
#define H_ 64
#define BT_ (B_*T_)

typedef __attribute__((ext_vector_type(8))) short bf16x8;
typedef __attribute__((ext_vector_type(4))) float f32x4;

__device__ __forceinline__ unsigned short f2bf(float x) {
    __hip_bfloat16 h = __float2bfloat16(x);   // RNE
    return __builtin_bit_cast(unsigned short, h);
}

__device__ __forceinline__ bf16x8 cvt8(float4 a, float4 b) {
    bf16x8 r;
    r[0] = (short)f2bf(a.x); r[1] = (short)f2bf(a.y);
    r[2] = (short)f2bf(a.z); r[3] = (short)f2bf(a.w);
    r[4] = (short)f2bf(b.x); r[5] = (short)f2bf(b.y);
    r[6] = (short)f2bf(b.z); r[7] = (short)f2bf(b.w);
    return r;
}

// ------------- W prep (coalesced LDS transpose): WT[m*64+n][k] = bf16(W_m[k][n])
__global__ __launch_bounds__(256) void wprep(
    const float* __restrict__ Wq, const float* __restrict__ Wk,
    const float* __restrict__ Wv, unsigned short* __restrict__ WT)
{
    __shared__ float tile[64][65];
    const int bidx = blockIdx.x;             // 36 = 3 m * 12 k-tiles
    const int m = bidx / 12, kt = bidx % 12;
    const float* __restrict__ W = (m == 0) ? Wq : (m == 1) ? Wk : Wv;
    const int t = threadIdx.x;
    const int n = t & 63, kr = t >> 6;
    #pragma unroll
    for (int r = kr; r < 64; r += 4)
        tile[r][n] = W[(size_t)(kt * 64 + r) * H_ + n];   // coalesced 256B rows
    __syncthreads();
    const int n2 = t >> 2, k0 = (t & 3) * 16;
    #pragma unroll
    for (int g = 0; g < 4; g++) {
        ushort4 u;
        u.x = f2bf(tile[k0 + g * 4 + 0][n2]);
        u.y = f2bf(tile[k0 + g * 4 + 1][n2]);
        u.z = f2bf(tile[k0 + g * 4 + 2][n2]);
        u.w = f2bf(tile[k0 + g * 4 + 3][n2]);
        *(ushort4*)(WT + (size_t)(m * 64 + n2) * C_ + kt * 64 + k0 + g * 4) = u;
    }
}

// ------------- QKV via MFMA: 2-wave K-split, x read exactly once per block ------
// Block = 16 tokens, 2 waves. Wave w owns k in [384w, 384w+384): 12 chunks of 32.
// Per chunk: ONE batch of 14 independent loads (2 x float4 + 12 W bf16x8), then
// 12 MFMAs — MLP from the batch (R7 showed the compiler deletes prefetch rings).
// No N-split: each x row is read by exactly one block (R7's FETCH 4x blowup).
// amdgpu_waves_per_eu(2,2): occupancy is grid-capped at 2 waves/SIMD anyway, so
// don't let the scheduler register-starve the load batches.
__global__ __launch_bounds__(128, 2)
__attribute__((amdgpu_waves_per_eu(2, 2)))
void qkv_kernel(
    const float* __restrict__ x, const unsigned short* __restrict__ WT,
    unsigned short* __restrict__ qo, unsigned short* __restrict__ ko,
    unsigned short* __restrict__ vTo)
{
    __shared__ float mrg[64][49];            // stride 49: lane*49%32 permutes banks
    const int tid  = threadIdx.x;
    const int w    = tid >> 6;
    const int lane = tid & 63;
    const int q16  = lane & 15, quad = lane >> 4;
    const int rowBase = blockIdx.x << 4;
    const int row  = rowBase + q16;
    const int b    = rowBase >> 11, t0 = rowBase & (T_ - 1);

    const float* __restrict__ xp = x + (size_t)row * C_ + w * 384 + quad * 8;
    const unsigned short* __restrict__ wp = WT + (size_t)q16 * C_ + w * 384 + quad * 8;

    f32x4 acc[12] = {};
    #pragma unroll
    for (int c = 0; c < 12; c++) {
        const int kk = c * 32;
        float4 xa = *(const float4*)(xp + kk);
        float4 xb = *(const float4*)(xp + kk + 4);
        bf16x8 wf[12];
        #pragma unroll
        for (int f = 0; f < 12; f++)
            wf[f] = *(const bf16x8*)(wp + kk + (size_t)(f * 16) * C_);
        bf16x8 xf = cvt8(xa, xb);
        #pragma unroll
        for (int f = 0; f < 12; f++)
            acc[f] = __builtin_amdgcn_mfma_f32_16x16x32_bf16(wf[f], xf, acc[f], 0, 0, 0);
    }

    // ---- merge the two K-halves (once per block; 2-way LDS banks = free)
    if (w == 1) {
        #pragma unroll
        for (int f = 0; f < 12; f++)
            #pragma unroll
            for (int r = 0; r < 4; r++) mrg[lane][f * 4 + r] = acc[f][r];
    }
    __syncthreads();
    if (w == 0) {
        #pragma unroll
        for (int f = 0; f < 12; f++)
            #pragma unroll
            for (int r = 0; r < 4; r++) acc[f][r] += mrg[lane][f * 4 + r];

        #pragma unroll
        for (int f = 0; f < 8; f++) {
            ushort4 u;
            u.x = f2bf(acc[f][0]); u.y = f2bf(acc[f][1]);
            u.z = f2bf(acc[f][2]); u.w = f2bf(acc[f][3]);
            unsigned short* __restrict__ dst = (f < 4) ? qo : ko;
            *(ushort4*)(dst + (size_t)row * H_ + (f & 3) * 16 + quad * 4) = u;
        }
        #pragma unroll
        for (int f = 8; f < 12; f++)
            #pragma unroll
            for (int r = 0; r < 4; r++) {
                int h = (f - 8) * 16 + quad * 4 + r;
                vTo[((size_t)(b * H_) + h) * T_ + t0 + q16] = f2bf(acc[f][r]);
            }
    }
}

// ------------- MFMA flash attention: 4 waves/block k-split, NO in-loop barriers -
__global__ __launch_bounds__(256) void attn_kernel(
    const unsigned short* __restrict__ qB, const unsigned short* __restrict__ kB,
    const unsigned short* __restrict__ vT, const float* __restrict__ mask,
    float* __restrict__ out)
{
    __shared__ __align__(16) unsigned short pS[4][16][88];  // wave-private P tiles
    __shared__ float oS[3][64][17];
    __shared__ float mlS[3][64][2];

    const int tid  = threadIdx.x;
    const int w    = tid >> 6;
    const int lane = tid & 63;
    const int q16  = lane & 15;
    const int quad = lane >> 4;
    const int bid  = blockIdx.x;
    const int b    = bid & 7;                    // batches interleaved
    const int qt   = 127 - (bid >> 3);           // heavy q-tiles first
    const int qrow = (qt << 4) + q16;

    const size_t qoff = ((size_t)(b * T_) + qrow) * H_ + quad * 8;
    bf16x8 qf0 = *(const bf16x8*)(qB + qoff);
    bf16x8 qf1 = *(const bf16x8*)(qB + qoff + 32);
    // fold 1/sqrt(64) and log2(e): softmax runs in base-2 domain
    const float maskv = mask[b * T_ + qrow] * 0.125f * 1.44269504f;

    f32x4 o[4] = {};
    float m_run = -__builtin_inff();
    float l_run = 0.f;

    const int niter = ((qt << 4) + 16 + 63) >> 6;   // 64-wide k tiles
    for (int kt = w; kt < niter; kt += 4) {
        const int kbase = kt << 6;

        // ---- K and V fragment loads (issued together; V covers softmax latency)
        bf16x8 kf[8], vf[8];
        #pragma unroll
        for (int sub = 0; sub < 4; sub++) {
            const unsigned short* kp = kB + ((size_t)(b * T_) + kbase + sub * 16 + q16) * H_ + quad * 8;
            kf[2 * sub]     = *(const bf16x8*)(kp);
            kf[2 * sub + 1] = *(const bf16x8*)(kp + 32);
        }
        #pragma unroll
        for (int ht = 0; ht < 4; ht++) {
            const unsigned short* vp = vT + ((size_t)(b * H_) + ht * 16 + q16) * T_ + kbase + quad * 8;
            vf[2 * ht]     = *(const bf16x8*)(vp);
            vf[2 * ht + 1] = *(const bf16x8*)(vp + 32);
        }

        // ---- S^T = K.Q^T : D[k_local][q]
        f32x4 sa[4] = {};
        #pragma unroll
        for (int sub = 0; sub < 4; sub++) {
            sa[sub] = __builtin_amdgcn_mfma_f32_16x16x32_bf16(kf[2 * sub],     qf0, sa[sub], 0, 0, 0);
            sa[sub] = __builtin_amdgcn_mfma_f32_16x16x32_bf16(kf[2 * sub + 1], qf1, sa[sub], 0, 0, 0);
        }

        // ---- reference semantics: s = mask*qk/8 (log2 dom); s==0 -> -inf; causal
        float s[16];
        #pragma unroll
        for (int sub = 0; sub < 4; sub++)
            #pragma unroll
            for (int r = 0; r < 4; r++) {
                int kidx = kbase + sub * 16 + quad * 4 + r;
                float sv = sa[sub][r] * maskv;
                sv = (sv == 0.f) ? -__builtin_inff() : sv;
                sv = (kidx > qrow) ? -__builtin_inff() : sv;
                s[sub * 4 + r] = sv;
            }

        // ---- online softmax (base-2). xor-16/32 reduce across the 4 lane-quads.
        float mx = s[0];
        #pragma unroll
        for (int i2 = 1; i2 < 16; i2++) mx = fmaxf(mx, s[i2]);
        mx = fmaxf(mx, __shfl_xor(mx, 16));
        mx = fmaxf(mx, __shfl_xor(mx, 32));
        float m_new = fmaxf(m_run, mx);
        float m_use = (m_new == -__builtin_inff()) ? 0.f : m_new;
        float alpha = exp2f(m_run - m_use);
        float p[16], psum = 0.f;
        #pragma unroll
        for (int i2 = 0; i2 < 16; i2++) { p[i2] = exp2f(s[i2] - m_use); psum += p[i2]; }
        psum += __shfl_xor(psum, 16);
        psum += __shfl_xor(psum, 32);
        l_run = l_run * alpha + psum;
        m_run = m_new;
        #pragma unroll
        for (int ht = 0; ht < 4; ht++)
            #pragma unroll
            for (int r = 0; r < 4; r++) o[ht][r] *= alpha;

        // ---- P^T -> wave-private LDS as P[q][k] bf16 (intra-wave: no barrier)
        #pragma unroll
        for (int sub = 0; sub < 4; sub++) {
            unsigned int lo = (unsigned int)f2bf(p[sub * 4 + 0]) | ((unsigned int)f2bf(p[sub * 4 + 1]) << 16);
            unsigned int hi = (unsigned int)f2bf(p[sub * 4 + 2]) | ((unsigned int)f2bf(p[sub * 4 + 3]) << 16);
            *(uint2*)&pS[w][q16][sub * 16 + quad * 4] = make_uint2(lo, hi);
        }
        bf16x8 pf0 = *(const bf16x8*)&pS[w][q16][quad * 8];
        bf16x8 pf1 = *(const bf16x8*)&pS[w][q16][32 + quad * 8];

        // ---- O^T += V^T.P^T
        #pragma unroll
        for (int ht = 0; ht < 4; ht++) {
            o[ht] = __builtin_amdgcn_mfma_f32_16x16x32_bf16(vf[2 * ht],     pf0, o[ht], 0, 0, 0);
            o[ht] = __builtin_amdgcn_mfma_f32_16x16x32_bf16(vf[2 * ht + 1], pf1, o[ht], 0, 0, 0);
        }
    }

    // ---- merge the 4 waves' online-softmax states
    if (w > 0) {
        mlS[w - 1][lane][0] = m_run;
        mlS[w - 1][lane][1] = l_run;
        #pragma unroll
        for (int ht = 0; ht < 4; ht++)
            #pragma unroll
            for (int r = 0; r < 4; r++) oS[w - 1][lane][ht * 4 + r] = o[ht][r];
    }
    __syncthreads();
    if (w == 0) {
        float mm[3], ll[3];
        float m = m_run;
        #pragma unroll
        for (int j = 0; j < 3; j++) {
            mm[j] = mlS[j][lane][0]; ll[j] = mlS[j][lane][1];
            m = fmaxf(m, mm[j]);
        }
        float mu = (m == -__builtin_inff()) ? 0.f : m;
        float a0 = exp2f(m_run - mu);
        float aj[3];
        float l = l_run * a0;
        #pragma unroll
        for (int j = 0; j < 3; j++) { aj[j] = exp2f(mm[j] - mu); l += ll[j] * aj[j]; }
        float invl = (l > 0.f) ? (1.f / l) : 0.f;   // fully-masked row -> 0
        #pragma unroll
        for (int ht = 0; ht < 4; ht++) {
            float4 ov;
            float vx = o[ht][0] * a0, vy = o[ht][1] * a0, vz = o[ht][2] * a0, vw2 = o[ht][3] * a0;
            #pragma unroll
            for (int j = 0; j < 3; j++) {
                vx += oS[j][lane][ht * 4 + 0] * aj[j];
                vy += oS[j][lane][ht * 4 + 1] * aj[j];
                vz += oS[j][lane][ht * 4 + 2] * aj[j];
                vw2 += oS[j][lane][ht * 4 + 3] * aj[j];
            }
            ov.x = vx * invl; ov.y = vy * invl; ov.z = vz * invl; ov.w = vw2 * invl;
            *(float4*)(out + ((size_t)(b * T_) + qrow) * H_ + ht * 16 + quad * 4) = ov;
        }
    }
}

extern "C" void kernel_launch(void* const* d_in, const int* in_sizes, int n_in,
                              void* d_out, int out_size, void* d_ws, size_t ws_size,
                              hipStream_t stream) {
    const float* x    = (const float*)d_in[0];
    const float* mask = (const float*)d_in[1];
    const float* Wq   = (const float*)d_in[2];
    const float* Wk   = (const float*)d_in[3];
    const float* Wv   = (const float*)d_in[4];
    float* out = (float*)d_out;

    unsigned short* qw = (unsigned short*)d_ws;            // bf16 [B,T,H]
    unsigned short* kw = qw + (size_t)BT_ * H_;            // bf16 [B,T,H]
    unsigned short* vw = kw + (size_t)BT_ * H_;            // bf16 [B,H,T]
    unsigned short* wt = vw + (size_t)BT_ * H_;            // bf16 [192][768]

    wprep<<<36, 256, 0, stream>>>(Wq, Wk, Wv, wt);
    qkv_kernel<<<BT_ / 16, 128, 0, stream>>>(x, wt, qw, kw, vw);
    attn_kernel<<<B_ * (T_ / 16), 256, 0, stream>>>(qw, kw, vw, mask, out);
}